// Round 1
// baseline (532.619 us; speedup 1.0000x reference)
//
#include <hip/hip_runtime.h>

// MoveModule: out[idx[k]] = (leaky_relu(nf[idx[k]] @ W1 + b1) @ W2 + b2), zeros elsewhere.
// N=500000, D=128, H=128, M=4, K=250000, fp32.
//
// fp32 has no MFMA on CDNA4 -> vector-ALU compute bound (8.45 GFLOP, ~54us floor).
// Strategy: W1 resident in LDS (64KB), 64-row x-tile in LDS (padded stride 132,
// conflict-free), per-thread 8x4 register block -> 1.5 B LDS per lane-FMA (< 2 B/FMA
// LDS ceiling). h tile reuses the x buffer for the tiny second layer.

#define D_DIM 128
#define H_DIM 128
#define M_DIM 4
#define ROWS 64
#define XSTR 132          // padded row stride (floats); 132*4B % 16 == 0 keeps b128 alignment
#define NTHREADS 256

__global__ void zero_out_kernel(float4* __restrict__ out, int n4) {
    int i = blockIdx.x * blockDim.x + threadIdx.x;
    int stride = gridDim.x * blockDim.x;
    float4 z = make_float4(0.f, 0.f, 0.f, 0.f);
    for (; i < n4; i += stride) out[i] = z;
}

__global__ __launch_bounds__(NTHREADS, 1)
void mlp_gs_kernel(const float* __restrict__ nf,
                   const int* __restrict__ idx,
                   const float* __restrict__ W1,
                   const float* __restrict__ b1,
                   const float* __restrict__ W2,
                   const float* __restrict__ b2,
                   float* __restrict__ out,
                   int K, int ntiles) {
    __shared__ float w1s[D_DIM * H_DIM];   // 64 KB, row-major [d][j]
    __shared__ float xh[ROWS * XSTR];      // x tile, then reused as h tile (33 KB)
    __shared__ float w2s[H_DIM * M_DIM];   // 2 KB, row-major [j][m]
    __shared__ float b1s[H_DIM];
    __shared__ float b2s[M_DIM];
    __shared__ int   idxs[ROWS];

    const int tid = threadIdx.x;

    // Stage weights once per block (L2-hot after first touch).
    for (int i = tid; i < D_DIM * H_DIM / 4; i += NTHREADS)
        ((float4*)w1s)[i] = ((const float4*)W1)[i];
    if (tid < H_DIM * M_DIM / 4) ((float4*)w2s)[tid] = ((const float4*)W2)[tid];
    if (tid < H_DIM) b1s[tid] = b1[tid];
    if (tid < M_DIM) b2s[tid] = b2[tid];

    // Layer-1 mapping: 32 col-groups (j0 = 4*cg), 8 row-groups (r0 = 8*rg).
    const int cg = tid & 31;
    const int rg = tid >> 5;
    const int j0 = cg * 4;
    const int r0 = rg * 8;

    for (int tile = blockIdx.x; tile < ntiles; tile += gridDim.x) {
        const int rowbase = tile * ROWS;
        __syncthreads();   // prev-iter layer-2 reads of xh/idxs done (also covers weight staging)

        if (tid < ROWS) {
            int g = rowbase + tid;
            idxs[tid] = (g < K) ? idx[g] : -1;
        }
        __syncthreads();

        // Gather 64 rows x 128 floats (coalesced 512B segments per row).
        #pragma unroll
        for (int i = 0; i < (ROWS * D_DIM / 4) / NTHREADS; ++i) {  // 8 iters
            int linear = tid + i * NTHREADS;
            int r  = linear >> 5;   // 32 float4 per row
            int f4 = linear & 31;
            int g = idxs[r];
            float4 v = make_float4(0.f, 0.f, 0.f, 0.f);
            if (g >= 0) v = *(const float4*)(nf + (long long)g * D_DIM + f4 * 4);
            *(float4*)(xh + r * XSTR + f4 * 4) = v;
        }
        __syncthreads();

        // Layer 1: acc[8 rows][4 cols], K-loop over d in steps of 4.
        float acc[8][4];
        #pragma unroll
        for (int r = 0; r < 8; ++r)
            #pragma unroll
            for (int j = 0; j < 4; ++j) acc[r][j] = b1s[j0 + j];

        #pragma unroll 4
        for (int d = 0; d < D_DIM; d += 4) {
            float4 wv[4];
            #pragma unroll
            for (int dd = 0; dd < 4; ++dd)
                wv[dd] = *(const float4*)(w1s + (d + dd) * H_DIM + j0);  // b128, full-bank
            #pragma unroll
            for (int r = 0; r < 8; ++r) {
                float4 xv = *(const float4*)(xh + (r0 + r) * XSTR + d);  // b128, wave-broadcast
                float xa[4] = {xv.x, xv.y, xv.z, xv.w};
                #pragma unroll
                for (int dd = 0; dd < 4; ++dd) {
                    acc[r][0] += xa[dd] * wv[dd].x;
                    acc[r][1] += xa[dd] * wv[dd].y;
                    acc[r][2] += xa[dd] * wv[dd].z;
                    acc[r][3] += xa[dd] * wv[dd].w;
                }
            }
        }

        __syncthreads();   // all x reads done before overwriting xh with h

        // leaky_relu, write h tile (b128 stores, conflict-free).
        #pragma unroll
        for (int r = 0; r < 8; ++r) {
            float4 hv;
            hv.x = acc[r][0] > 0.f ? acc[r][0] : acc[r][0] * 0.01f;
            hv.y = acc[r][1] > 0.f ? acc[r][1] : acc[r][1] * 0.01f;
            hv.z = acc[r][2] > 0.f ? acc[r][2] : acc[r][2] * 0.01f;
            hv.w = acc[r][3] > 0.f ? acc[r][3] : acc[r][3] * 0.01f;
            *(float4*)(xh + (r0 + r) * XSTR + j0) = hv;
        }
        __syncthreads();

        // Layer 2: 64 rows x 4 outputs = 256 = one per thread. 1/32 of the FLOPs.
        const int r2 = tid >> 2;
        const int m2 = tid & 3;
        float p = 0.f;
        #pragma unroll 8
        for (int j = 0; j < H_DIM; j += 4) {
            float4 hv = *(const float4*)(xh + r2 * XSTR + j);  // 2-way conflict = free
            p += hv.x * w2s[(j + 0) * M_DIM + m2];
            p += hv.y * w2s[(j + 1) * M_DIM + m2];
            p += hv.z * w2s[(j + 2) * M_DIM + m2];
            p += hv.w * w2s[(j + 3) * M_DIM + m2];
        }
        int g2 = rowbase + r2;
        if (g2 < K) {
            out[(long long)idxs[r2] * M_DIM + m2] = p + b2s[m2];
        }
    }
}

extern "C" void kernel_launch(void* const* d_in, const int* in_sizes, int n_in,
                              void* d_out, int out_size, void* d_ws, size_t ws_size,
                              hipStream_t stream) {
    const float* nf  = (const float*)d_in[0];
    const int*   idx = (const int*)d_in[1];   // harness contract: integer -> const int*
    const float* W1  = (const float*)d_in[2];
    const float* b1  = (const float*)d_in[3];
    const float* W2  = (const float*)d_in[4];
    const float* b2  = (const float*)d_in[5];
    float* out = (float*)d_out;
    const int K = in_sizes[1];

    // d_out is poisoned 0xAA before every launch -> zero it (8 MB, ~1.3us).
    int n4 = out_size / 4;   // out_size = 2,000,000, divisible by 4
    hipLaunchKernelGGL(zero_out_kernel, dim3(512), dim3(256), 0, stream,
                       (float4*)out, n4);

    int ntiles = (K + ROWS - 1) / ROWS;
    int grid = ntiles < 256 ? ntiles : 256;   // 1 block/CU (100KB LDS), grid-stride tiles
    hipLaunchKernelGGL(mlp_gs_kernel, dim3(grid), dim3(256), 0, stream,
                       nf, idx, W1, b1, W2, b2, out, K, ntiles);
}

// Round 4
// 409.441 us; speedup vs baseline: 1.3008x; 1.3008x over previous
//
#include <hip/hip_runtime.h>

// MoveModule: out[idx[k]] = (leaky_relu(nf[idx[k]] @ W1 + b1) @ W2 + b2), zeros elsewhere.
// N=500000, D=128, H=128, M=4, K=250000, fp32 (no fp32 MFMA on CDNA4 -> VALU-bound, 54us floor).
//
// R1 post-mortem: 277us, VALUBusy=30%, Occupancy=11% (1 blk/CU x 4 waves). Latency-bound,
// not LDS/HBM-bound. R2: 512 thr (8 waves/CU), double-buffered x/h tile, T14 async-stage
// (gather next tile into regs during layer-1 compute, ds_write after barrier), 2 barriers/tile.
// (R2/R3 benches never ran - GPU acquisition timeouts; resubmitted unchanged.)

#define D_DIM 128
#define H_DIM 128
#define M_DIM 4
#define ROWS 64
#define XSTR 132          // padded row stride: (132*r)%32 = (4r)%32 -> layer-2 row reads conflict-free
#define NT 512

__global__ void zero_out_kernel(float4* __restrict__ out, int n4) {
    int i = blockIdx.x * blockDim.x + threadIdx.x;
    int stride = gridDim.x * blockDim.x;
    float4 z = make_float4(0.f, 0.f, 0.f, 0.f);
    for (; i < n4; i += stride) out[i] = z;
}

__global__ __launch_bounds__(NT, 2)
void mlp_pipe_kernel(const float* __restrict__ nf,
                     const int* __restrict__ idx,
                     const float* __restrict__ W1,
                     const float* __restrict__ b1,
                     const float* __restrict__ W2,
                     const float* __restrict__ b2,
                     float* __restrict__ out,
                     int K, int ntiles) {
    __shared__ float w1s[D_DIM * H_DIM];     // 64 KB, [d][j]
    __shared__ float xh[2][ROWS * XSTR];     // 2 x 33.8 KB double buffer (x, then h)
    __shared__ float w2s[H_DIM * M_DIM];     // [j][m]
    __shared__ float b1s[H_DIM];
    __shared__ float b2s[M_DIM];
    __shared__ int   idxs[2][ROWS];

    const int tid = threadIdx.x;

    // Stage weights once per block.
    for (int i = tid; i < D_DIM * H_DIM / 4; i += NT)
        ((float4*)w1s)[i] = ((const float4*)W1)[i];
    if (tid < H_DIM * M_DIM / 4) ((float4*)w2s)[tid] = ((const float4*)W2)[tid];
    if (tid < H_DIM) b1s[tid] = b1[tid];
    if (tid < M_DIM) b2s[tid] = b2[tid];

    // Layer-1 mapping: 32 col-groups x 16 row-groups; 4 rows x 4 cols per thread.
    const int cg = tid & 31, rg = tid >> 5;
    const int j0 = cg * 4, r0 = rg * 4;
    // Gather mapping: thread handles 4 float4s: rows gr+16i, float4-slot gf4.
    const int gr = tid >> 5;      // 0..15
    const int gf4 = tid & 31;     // 0..31

    const int stride_t = gridDim.x;
    int nidx[4];
    float4 px[4];

    // ---- Prologue: stage the block's first tile into buf 0; prefetch idx for tile+stride.
    {
        int t = blockIdx.x;
        #pragma unroll
        for (int i = 0; i < 4; ++i) {
            int r = gr + 16 * i;
            int g = t * ROWS + r;
            nidx[i] = (t < ntiles && g < K) ? idx[g] : -1;
        }
        #pragma unroll
        for (int i = 0; i < 4; ++i) {
            px[i] = make_float4(0.f, 0.f, 0.f, 0.f);
            if (nidx[i] >= 0)
                px[i] = *(const float4*)(nf + (long long)nidx[i] * D_DIM + gf4 * 4);
        }
        #pragma unroll
        for (int i = 0; i < 4; ++i) {
            int r = gr + 16 * i;
            *(float4*)(&xh[0][r * XSTR + gf4 * 4]) = px[i];
            if (gf4 == 0) idxs[0][r] = nidx[i];
        }
        int t1 = t + stride_t;
        #pragma unroll
        for (int i = 0; i < 4; ++i) {
            int r = gr + 16 * i;
            int g = t1 * ROWS + r;
            nidx[i] = (t1 < ntiles && g < K) ? idx[g] : -1;
        }
    }
    __syncthreads();

    int buf = 0;
    for (int t = blockIdx.x; t < ntiles; t += stride_t, buf ^= 1) {
        // --- Issue next tile's gather into registers NOW (hides HBM latency under layer 1).
        #pragma unroll
        for (int i = 0; i < 4; ++i) {
            px[i] = make_float4(0.f, 0.f, 0.f, 0.f);
            if (nidx[i] >= 0)
                px[i] = *(const float4*)(nf + (long long)nidx[i] * D_DIM + gf4 * 4);
        }

        // --- Layer 1: acc[4 rows][4 cols] over d.
        float acc[4][4];
        #pragma unroll
        for (int r = 0; r < 4; ++r)
            #pragma unroll
            for (int j = 0; j < 4; ++j) acc[r][j] = b1s[j0 + j];

        const float* xb = &xh[buf][0];
        #pragma unroll 4
        for (int d = 0; d < D_DIM; d += 4) {
            float4 wv[4];
            #pragma unroll
            for (int dd = 0; dd < 4; ++dd)
                wv[dd] = *(const float4*)(w1s + (d + dd) * H_DIM + j0);   // spans all banks
            #pragma unroll
            for (int r = 0; r < 4; ++r) {
                float4 xv = *(const float4*)(xb + (r0 + r) * XSTR + d);   // half-wave broadcast
                float xa[4] = {xv.x, xv.y, xv.z, xv.w};
                #pragma unroll
                for (int dd = 0; dd < 4; ++dd) {
                    acc[r][0] += xa[dd] * wv[dd].x;
                    acc[r][1] += xa[dd] * wv[dd].y;
                    acc[r][2] += xa[dd] * wv[dd].z;
                    acc[r][3] += xa[dd] * wv[dd].w;
                }
            }
        }
        __syncthreads();   // barrier 1: xh[buf] x-reads done; xh[buf^1] free (prev layer-2 done)

        // --- leaky_relu -> h tile (overwrites x in xh[buf]).
        #pragma unroll
        for (int r = 0; r < 4; ++r) {
            float4 hv;
            hv.x = acc[r][0] > 0.f ? acc[r][0] : acc[r][0] * 0.01f;
            hv.y = acc[r][1] > 0.f ? acc[r][1] : acc[r][1] * 0.01f;
            hv.z = acc[r][2] > 0.f ? acc[r][2] : acc[r][2] * 0.01f;
            hv.w = acc[r][3] > 0.f ? acc[r][3] : acc[r][3] * 0.01f;
            *(float4*)(&xh[buf][(r0 + r) * XSTR + j0]) = hv;
        }

        // --- Stage prefetched x_{t+stride} into the other buffer (vmcnt wait auto-inserted;
        //     the loads had the whole layer-1 phase to land).
        #pragma unroll
        for (int i = 0; i < 4; ++i) {
            int r = gr + 16 * i;
            *(float4*)(&xh[buf ^ 1][r * XSTR + gf4 * 4]) = px[i];
            if (gf4 == 0) idxs[buf ^ 1][r] = nidx[i];
        }

        // --- Prefetch idx for t + 2*stride.
        int t2 = t + 2 * stride_t;
        #pragma unroll
        for (int i = 0; i < 4; ++i) {
            int r = gr + 16 * i;
            int g = t2 * ROWS + r;
            nidx[i] = (t2 < ntiles && g < K) ? idx[g] : -1;
        }
        __syncthreads();   // barrier 2: h visible, next x staged

        // --- Layer 2: 64 rows x 4 outputs = 256 -> one per thread (tid < 256).
        if (tid < 256) {
            const int r2 = tid >> 2, m2 = tid & 3;
            float p = 0.f;
            const float* hb = &xh[buf][r2 * XSTR];
            #pragma unroll 8
            for (int j = 0; j < H_DIM; j += 4) {
                float4 hv = *(const float4*)(hb + j);   // 4-lane broadcast, banks rotate by 4/row
                p += hv.x * w2s[(j + 0) * M_DIM + m2];
                p += hv.y * w2s[(j + 1) * M_DIM + m2];
                p += hv.z * w2s[(j + 2) * M_DIM + m2];
                p += hv.w * w2s[(j + 3) * M_DIM + m2];
            }
            int g2 = t * ROWS + r2;
            int gidx = idxs[buf][r2];
            if (g2 < K && gidx >= 0)
                out[(long long)gidx * M_DIM + m2] = p + b2s[m2];
        }
    }
}

extern "C" void kernel_launch(void* const* d_in, const int* in_sizes, int n_in,
                              void* d_out, int out_size, void* d_ws, size_t ws_size,
                              hipStream_t stream) {
    const float* nf  = (const float*)d_in[0];
    const int*   idx = (const int*)d_in[1];
    const float* W1  = (const float*)d_in[2];
    const float* b1  = (const float*)d_in[3];
    const float* W2  = (const float*)d_in[4];
    const float* b2  = (const float*)d_in[5];
    float* out = (float*)d_out;
    const int K = in_sizes[1];

    // d_out is poisoned 0xAA before every launch -> zero it.
    int n4 = out_size / 4;
    hipLaunchKernelGGL(zero_out_kernel, dim3(1024), dim3(256), 0, stream,
                       (float4*)out, n4);

    int ntiles = (K + ROWS - 1) / ROWS;
    int grid = ntiles < 256 ? ntiles : 256;   // 1 blk/CU (136 KB LDS), grid-stride tiles
    hipLaunchKernelGGL(mlp_pipe_kernel, dim3(grid), dim3(NT), 0, stream,
                       nf, idx, W1, b1, W2, b2, out, K, ntiles);
}